// Round 9
// baseline (1767.546 us; speedup 1.0000x reference)
//
#include <hip/hip_runtime.h>

#define T_SEQ  2048
#define TK_SEQ 2049
#define SCALE_F 0.08838834764831845f

// ---------------------------------------------------------------------------
// Naive tiled f32 GEMM: C[M,N] = A[M,K] * B[N,K]^T.  64x64 tile, 256 threads,
// 4x4 outputs/thread, K-tile 16.  f32 in, f32 out.
// ---------------------------------------------------------------------------
__global__ __launch_bounds__(256) void ngemm_bt(const float* __restrict__ A,
                                                const float* __restrict__ B,
                                                float* __restrict__ C,
                                                int M, int N, int K) {
  __shared__ float As[64 * 17];
  __shared__ float Bs[64 * 17];
  const int tid = threadIdx.x;
  const int tx = tid & 15, ty = tid >> 4;
  const int m0 = blockIdx.y << 6;
  const int n0 = blockIdx.x << 6;

  float acc[4][4] = {};

  for (int k0 = 0; k0 < K; k0 += 16) {
    __syncthreads();
#pragma unroll
    for (int v = 0; v < 4; ++v) {
      int id = tid + (v << 8);
      int r = id >> 4, c = id & 15;
      As[r * 17 + c] = A[(size_t)(m0 + r) * K + k0 + c];
      Bs[r * 17 + c] = B[(size_t)(n0 + r) * K + k0 + c];
    }
    __syncthreads();
#pragma unroll
    for (int kk = 0; kk < 16; ++kk) {
      float a[4], b[4];
#pragma unroll
      for (int i = 0; i < 4; ++i) a[i] = As[(ty * 4 + i) * 17 + kk];
#pragma unroll
      for (int j = 0; j < 4; ++j) b[j] = Bs[(tx * 4 + j) * 17 + kk];
#pragma unroll
      for (int i = 0; i < 4; ++i)
#pragma unroll
        for (int j = 0; j < 4; ++j) acc[i][j] += a[i] * b[j];
    }
  }
#pragma unroll
  for (int i = 0; i < 4; ++i)
#pragma unroll
    for (int j = 0; j < 4; ++j)
      C[(size_t)(m0 + ty * 4 + i) * N + n0 + tx * 4 + j] = acc[i][j];
}

// ---------------------------------------------------------------------------
// RoPE + assemble q(T,H,D) / k(Tk,G,D) / v(Tk,G,D), ALL f32; sink at j=0,
// sink NOT rotated (ref concatenates after rope).
// qkv layout per t (jax reshape (G, QPK+2, D)): g*768 + {qi*128, 512, 640} + d
// ---------------------------------------------------------------------------
__global__ void rope_prep_f32(const float* __restrict__ qkv,
                              const float* __restrict__ cosb,
                              const float* __restrict__ sinb,
                              const float* __restrict__ ksink,
                              const float* __restrict__ vsink,
                              float* __restrict__ qf,
                              float* __restrict__ kf,
                              float* __restrict__ vf) {
  const int NQ = T_SEQ * 2048;          // 4,194,304
  const int NK = TK_SEQ * 512;          // 1,049,088
  int idx = blockIdx.x * 256 + threadIdx.x;
  if (idx < NQ) {
    int t = idx >> 11, rem = idx & 2047;
    int h = rem >> 7, d = rem & 127;
    int g = h >> 2, qi = h & 3;
    const float* src = qkv + (size_t)t * 3072 + g * 768 + qi * 128;
    float val;
    if (d < 64) {
      val = src[d] * cosb[t * 64 + d] - src[d + 64] * sinb[t * 64 + d];
    } else {
      int dd = d - 64;
      val = src[dd] * sinb[t * 64 + dd] + src[d] * cosb[t * 64 + dd];
    }
    qf[idx] = val;
  } else if (idx < NQ + NK) {
    int r = idx - NQ;
    int j = r >> 9, rem = r & 511;
    int g = rem >> 7, d = rem & 127;
    float val;
    if (j == 0) {
      val = ksink[(g << 7) + d];
    } else {
      int t = j - 1;
      const float* src = qkv + (size_t)t * 3072 + g * 768 + 512;
      if (d < 64) {
        val = src[d] * cosb[t * 64 + d] - src[d + 64] * sinb[t * 64 + d];
      } else {
        int dd = d - 64;
        val = src[dd] * sinb[t * 64 + dd] + src[d] * cosb[t * 64 + dd];
      }
    }
    kf[r] = val;
  } else if (idx < NQ + 2 * NK) {
    int r = idx - NQ - NK;
    int j = r >> 9, rem = r & 511;
    int g = rem >> 7, d = rem & 127;
    vf[r] = (j == 0) ? vsink[(g << 7) + d]
                     : qkv[(size_t)(j - 1) * 3072 + g * 768 + 640 + d];
  }
}

// ---------------------------------------------------------------------------
// Naive attention, pure f32: one wave per (t, group); 4 heads per wave as
// 16-lane subgroups. Exact mask via loop bounds: j in [max(0, t-1022), t+1].
// ---------------------------------------------------------------------------
__global__ __launch_bounds__(256) void attn_naive_f32(const float* __restrict__ qf,
                                                      const float* __restrict__ kf,
                                                      const float* __restrict__ vf,
                                                      float* __restrict__ of) {
  const int wid  = blockIdx.x * 4 + (threadIdx.x >> 6);   // 0..8191
  const int t    = wid >> 2;
  const int g    = wid & 3;
  const int lane = threadIdx.x & 63;
  const int hq   = lane >> 4;
  const int h    = g * 4 + hq;
  const int dq   = (lane & 15) << 3;

  float q[8];
#pragma unroll
  for (int e = 0; e < 8; ++e) q[e] = qf[(size_t)t * 2048 + h * 128 + dq + e];

  float m = -1e30f, l = 0.f, o[8] = {};
  const int jlo = (t >= 1023) ? (t - 1022) : 0;
  const int jhi = t + 1;
  for (int j = jlo; j <= jhi; ++j) {
    const float* krow = &kf[(size_t)j * 512 + g * 128 + dq];
    float s = 0.f;
#pragma unroll
    for (int e = 0; e < 8; ++e) s += q[e] * krow[e];
    s += __shfl_xor(s, 1, 64);     // reduce across the 16-lane subgroup
    s += __shfl_xor(s, 2, 64);
    s += __shfl_xor(s, 4, 64);
    s += __shfl_xor(s, 8, 64);
    s *= SCALE_F;
    float mn = fmaxf(m, s);
    float a  = __expf(m - mn);
    float p  = __expf(s - mn);
    l = l * a + p;
    m = mn;
    const float* vrow = &vf[(size_t)j * 512 + g * 128 + dq];
#pragma unroll
    for (int e = 0; e < 8; ++e) o[e] = o[e] * a + p * vrow[e];
  }
  const float inv = 1.f / l;
#pragma unroll
  for (int e = 0; e < 8; ++e)
    of[(size_t)t * 2048 + h * 128 + dq + e] = o[e] * inv;
}

extern "C" void kernel_launch(void* const* d_in, const int* in_sizes, int n_in,
                              void* d_out, int out_size, void* d_ws, size_t ws_size,
                              hipStream_t stream) {
  const float* x     = (const float*)d_in[0];   // (2048, 2048) f32
  const float* cosb  = (const float*)d_in[1];   // (2048, 64)   f32
  const float* sinb  = (const float*)d_in[2];   // (2048, 64)   f32
  const float* Wa    = (const float*)d_in[3];   // (3072, 2048) f32
  const float* Wp    = (const float*)d_in[4];   // (2048, 2048) f32
  const float* ksink = (const float*)d_in[5];   // (512,)       f32
  const float* vsink = (const float*)d_in[6];   // (512,)       f32
  float* y = (float*)d_out;                     // (2048, 2048) f32  <-- THE FIX

  char* ws = (char*)d_ws;
  float* qkv = (float*)ws;                      // 25,165,824 B
  float* qf  = (float*)(ws + 25165824);         // 16,777,216 B
  float* kf  = (float*)(ws + 41943040);         //  4,196,352 B
  float* vf  = (float*)(ws + 46139392);         //  4,196,352 B
  float* of  = (float*)(ws + 50335744);         // 16,777,216 B -> 67,112,960 total

  // 1. qkv = x @ W_attn^T  (pure f32)
  ngemm_bt<<<dim3(48, 32), 256, 0, stream>>>(x, Wa, qkv, 2048, 3072, 2048);
  // 2. RoPE + sink assembly (pure f32)
  rope_prep_f32<<<24580, 256, 0, stream>>>(qkv, cosb, sinb, ksink, vsink, qf, kf, vf);
  // 3. naive attention (pure f32)
  attn_naive_f32<<<2048, 256, 0, stream>>>(qf, kf, vf, of);
  // 4. y = o @ W_proj^T  (pure f32, f32 store to d_out)
  ngemm_bt<<<dim3(32, 32), 256, 0, stream>>>(of, Wp, y, 2048, 2048, 2048);
}